// Round 2
// baseline (1691.394 us; speedup 1.0000x reference)
//
#include <hip/hip_runtime.h>
#include <math.h>

#define NN 50000
#define NE 640000
#define H 128
#define ZDIM 280      // 2*H + 20 + 4
#define ZSTR 288      // LDS stride for z (float4-aligned)
#define BSTR 132      // LDS stride for 128-wide buffers
#define EPB 32        // edges per block
#define NPB 32        // nodes per block
#define NZSTR 264     // LDS stride for node 256-wide input

__device__ __forceinline__ float silu_f(float v) {
    return v / (1.0f + __expf(-v));
}

__device__ __forceinline__ float f4get(const float4& v, int j) {
    return j == 0 ? v.x : (j == 1 ? v.y : (j == 2 ? v.z : v.w));
}

// Register-tiled GEMM fragment: out[4][4] += in_lds[4 rows][K] @ W[K][H] tile.
// Thread (tx,ty): rows ty*4..+3, cols tx*4..+3.
template<int K, int STR>
__device__ __forceinline__ void gemm_tile(const float* __restrict__ in_lds,
                                          const float* __restrict__ W,
                                          int tx, int ty, float acc[4][4]) {
    const float* r0 = in_lds + (ty * 4 + 0) * STR;
    const float* r1 = in_lds + (ty * 4 + 1) * STR;
    const float* r2 = in_lds + (ty * 4 + 2) * STR;
    const float* r3 = in_lds + (ty * 4 + 3) * STR;
    const float* wp = W + tx * 4;
    #pragma unroll 2
    for (int i = 0; i < K; i += 4) {
        float4 z0 = *(const float4*)(r0 + i);
        float4 z1 = *(const float4*)(r1 + i);
        float4 z2 = *(const float4*)(r2 + i);
        float4 z3 = *(const float4*)(r3 + i);
        #pragma unroll
        for (int j = 0; j < 4; j++) {
            float4 w = *(const float4*)(wp + (i + j) * H);
            float a0 = f4get(z0, j), a1 = f4get(z1, j), a2 = f4get(z2, j), a3 = f4get(z3, j);
            acc[0][0] += a0 * w.x; acc[0][1] += a0 * w.y; acc[0][2] += a0 * w.z; acc[0][3] += a0 * w.w;
            acc[1][0] += a1 * w.x; acc[1][1] += a1 * w.y; acc[1][2] += a1 * w.z; acc[1][3] += a1 * w.w;
            acc[2][0] += a2 * w.x; acc[2][1] += a2 * w.y; acc[2][2] += a2 * w.z; acc[2][3] += a2 * w.w;
            acc[3][0] += a3 * w.x; acc[3][1] += a3 * w.y; acc[3][2] += a3 * w.z; acc[3][3] += a3 * w.w;
        }
    }
}

__global__ __launch_bounds__(256) void zero_kernel(float4* __restrict__ p, int n4) {
    int i = blockIdx.x * 256 + threadIdx.x;
    if (i < n4) p[i] = make_float4(0.f, 0.f, 0.f, 0.f);
}

__global__ __launch_bounds__(256) void edge_kernel(
    const float* __restrict__ h, const float* __restrict__ x,
    const int* __restrict__ ei, const float* __restrict__ edge_attr,
    const float* __restrict__ We1, const float* __restrict__ be1,
    const float* __restrict__ We2, const float* __restrict__ be2,
    const float* __restrict__ Winf, const float* __restrict__ binf,
    const float* __restrict__ Wx1, const float* __restrict__ bx1,
    const float* __restrict__ Wx2,
    float* __restrict__ mi, float* __restrict__ dx)
{
    __shared__ float z[EPB * ZSTR];
    __shared__ float bufA[EPB * BSTR];
    __shared__ float bufB[EPB * BSTR];
    __shared__ float relx_s[EPB][3];
    __shared__ float eij_s[EPB];
    __shared__ float xg_s[EPB];
    __shared__ int dst_s[EPB];
    __shared__ int src_s[EPB];

    const int t = threadIdx.x;
    const int e0 = blockIdx.x * EPB;

    if (t < EPB) {
        src_s[t] = ei[e0 + t];
        dst_s[t] = ei[NE + e0 + t];
    }
    __syncthreads();

    // Gather h[dst] -> z[0:128], h[src] -> z[128:256]; 8 threads per edge.
    {
        int e = t >> 3, l = t & 7;
        int s = src_s[e], d = dst_s[e];
        const float4* hd = (const float4*)(h + (size_t)d * H);
        const float4* hs = (const float4*)(h + (size_t)s * H);
        float4* zr = (float4*)(z + e * ZSTR);
        #pragma unroll
        for (int j = 0; j < 4; j++) {
            zr[l * 4 + j]      = hd[l * 4 + j];
            zr[32 + l * 4 + j] = hs[l * 4 + j];
        }
    }
    // Geometry + gaussian smearing + edge_attr; one thread per edge.
    if (t < EPB) {
        int s = src_s[t], d = dst_s[t];
        float rx = x[d * 3 + 0] - x[s * 3 + 0];
        float ry = x[d * 3 + 1] - x[s * 3 + 1];
        float rz = x[d * 3 + 2] - x[s * 3 + 2];
        float d2 = rx * rx + ry * ry + rz * rz;
        float dd = sqrtf(d2 + 1e-8f);
        float inv = 1.0f / (dd + 1.0f);
        relx_s[t][0] = rx * inv;
        relx_s[t][1] = ry * inv;
        relx_s[t][2] = rz * inv;
        const float step = 10.0f / 19.0f;
        const float coeff = -0.5f / (step * step);
        #pragma unroll
        for (int g = 0; g < 20; g++) {
            float df = dd - step * (float)g;
            z[t * ZSTR + 256 + g] = __expf(coeff * df * df);
        }
        #pragma unroll
        for (int j = 0; j < 4; j++)
            z[t * ZSTR + 276 + j] = edge_attr[(size_t)(e0 + t) * 4 + j];
    }
    __syncthreads();

    const int tx = t & 31, ty = t >> 5;

    // Layer 1: z[32][280] @ We1[280][128] -> silu -> bufA
    {
        float acc[4][4] = {{0}};
        gemm_tile<ZDIM, ZSTR>(z, We1, tx, ty, acc);
        float4 b = *(const float4*)(be1 + tx * 4);
        #pragma unroll
        for (int e = 0; e < 4; e++) {
            float4 o;
            o.x = silu_f(acc[e][0] + b.x);
            o.y = silu_f(acc[e][1] + b.y);
            o.z = silu_f(acc[e][2] + b.z);
            o.w = silu_f(acc[e][3] + b.w);
            *(float4*)(bufA + (ty * 4 + e) * BSTR + tx * 4) = o;
        }
    }
    __syncthreads();

    // Layer 2: bufA @ We2 -> silu -> bufB (mij)
    {
        float acc[4][4] = {{0}};
        gemm_tile<H, BSTR>(bufA, We2, tx, ty, acc);
        float4 b = *(const float4*)(be2 + tx * 4);
        #pragma unroll
        for (int e = 0; e < 4; e++) {
            float4 o;
            o.x = silu_f(acc[e][0] + b.x);
            o.y = silu_f(acc[e][1] + b.y);
            o.z = silu_f(acc[e][2] + b.z);
            o.w = silu_f(acc[e][3] + b.w);
            *(float4*)(bufB + (ty * 4 + e) * BSTR + tx * 4) = o;
        }
    }
    __syncthreads();

    // eij = sigmoid(mij . Winf + binf); 8 threads per edge.
    {
        int e = t >> 3, l = t & 7;
        float s = 0.0f;
        #pragma unroll
        for (int j = 0; j < 16; j++) {
            int k = l + j * 8;
            s += bufB[e * BSTR + k] * Winf[k];
        }
        s += __shfl_down(s, 4, 8);
        s += __shfl_down(s, 2, 8);
        s += __shfl_down(s, 1, 8);
        if (l == 0) eij_s[e] = 1.0f / (1.0f + __expf(-(s + binf[0])));
    }

    // Coord layer 1: mij @ Wx1 -> silu -> bufA (l3)
    {
        float acc[4][4] = {{0}};
        gemm_tile<H, BSTR>(bufB, Wx1, tx, ty, acc);
        float4 b = *(const float4*)(bx1 + tx * 4);
        #pragma unroll
        for (int e = 0; e < 4; e++) {
            float4 o;
            o.x = silu_f(acc[e][0] + b.x);
            o.y = silu_f(acc[e][1] + b.y);
            o.z = silu_f(acc[e][2] + b.z);
            o.w = silu_f(acc[e][3] + b.w);
            *(float4*)(bufA + (ty * 4 + e) * BSTR + tx * 4) = o;
        }
    }
    __syncthreads();

    // xg = tanh(l3 . Wx2); 8 threads per edge.
    {
        int e = t >> 3, l = t & 7;
        float s = 0.0f;
        #pragma unroll
        for (int j = 0; j < 16; j++) {
            int k = l + j * 8;
            s += bufA[e * BSTR + k] * Wx2[k];
        }
        s += __shfl_down(s, 4, 8);
        s += __shfl_down(s, 2, 8);
        s += __shfl_down(s, 1, 8);
        if (l == 0) xg_s[e] = tanhf(s);
    }
    __syncthreads();

    // Segment-sum via atomics.
    {
        int k = t & 127, eh = t >> 7;
        for (int e = eh; e < EPB; e += 2) {
            atomicAdd(&mi[(size_t)dst_s[e] * H + k], bufB[e * BSTR + k] * eij_s[e]);
        }
        if (t < EPB * 3) {
            int e = t / 3, dim = t % 3;
            atomicAdd(&dx[(size_t)dst_s[e] * 3 + dim], relx_s[e][dim] * xg_s[e]);
        }
    }
}

// Reads mi/dx from d_out and overwrites the same locations with h_out/x_out.
// Safe: each block stages its nodes' mi into LDS (and dx into registers)
// before any write; blocks never touch other blocks' nodes.
__global__ __launch_bounds__(256) void node_kernel(
    const float* __restrict__ h, const float* __restrict__ x,
    const float* __restrict__ mask,
    const float* __restrict__ Wn1, const float* __restrict__ bn1,
    const float* __restrict__ Wn2, const float* __restrict__ bn2,
    float* __restrict__ mi_hout, float* __restrict__ dx_xout)
{
    __shared__ float nz[NPB * NZSTR];
    __shared__ float buf[NPB * BSTR];

    const int t = threadIdx.x;
    const int n0 = blockIdx.x * NPB;

    // Load nz = [mi, h]; 8 threads per node.
    {
        int r = t >> 3, l = t & 7;
        int n = n0 + r;
        float4* dst4 = (float4*)(nz + r * NZSTR);
        if (n < NN) {
            const float4* mi4 = (const float4*)(mi_hout + (size_t)n * H);
            const float4* h4  = (const float4*)(h + (size_t)n * H);
            #pragma unroll
            for (int j = 0; j < 4; j++) {
                dst4[l * 4 + j]      = mi4[l * 4 + j];
                dst4[32 + l * 4 + j] = h4[l * 4 + j];
            }
        } else {
            float4 zf = {0.f, 0.f, 0.f, 0.f};
            #pragma unroll
            for (int j = 0; j < 4; j++) {
                dst4[l * 4 + j] = zf;
                dst4[32 + l * 4 + j] = zf;
            }
        }
    }

    // x_out = x + dx * mask : read dx before barrier, write after compute.
    float xo = 0.f;
    int xn = -1, xdim = 0;
    if (t < NPB * 3) {
        int r = t / 3; xdim = t % 3;
        int n = n0 + r;
        if (n < NN) {
            xn = n;
            xo = x[(size_t)n * 3 + xdim] + dx_xout[(size_t)n * 3 + xdim] * mask[n];
        }
    }
    __syncthreads();

    if (xn >= 0) dx_xout[(size_t)xn * 3 + xdim] = xo;

    const int tx = t & 31, ty = t >> 5;

    // Node layer 1: nz[32][256] @ Wn1 -> silu -> buf
    {
        float acc[4][4] = {{0}};
        gemm_tile<2 * H, NZSTR>(nz, Wn1, tx, ty, acc);
        float4 b = *(const float4*)(bn1 + tx * 4);
        #pragma unroll
        for (int e = 0; e < 4; e++) {
            float4 o;
            o.x = silu_f(acc[e][0] + b.x);
            o.y = silu_f(acc[e][1] + b.y);
            o.z = silu_f(acc[e][2] + b.z);
            o.w = silu_f(acc[e][3] + b.w);
            *(float4*)(buf + (ty * 4 + e) * BSTR + tx * 4) = o;
        }
    }
    __syncthreads();

    // Node layer 2 + residual: h_out = h + buf @ Wn2 + bn2 (in place over mi)
    {
        float acc[4][4] = {{0}};
        gemm_tile<H, BSTR>(buf, Wn2, tx, ty, acc);
        float4 b = *(const float4*)(bn2 + tx * 4);
        #pragma unroll
        for (int e = 0; e < 4; e++) {
            int n = n0 + ty * 4 + e;
            if (n < NN) {
                const float4 hv = *(const float4*)(h + (size_t)n * H + tx * 4);
                float4 o;
                o.x = hv.x + acc[e][0] + b.x;
                o.y = hv.y + acc[e][1] + b.y;
                o.z = hv.z + acc[e][2] + b.z;
                o.w = hv.w + acc[e][3] + b.w;
                *(float4*)(mi_hout + (size_t)n * H + tx * 4) = o;
            }
        }
    }
}

extern "C" void kernel_launch(void* const* d_in, const int* in_sizes, int n_in,
                              void* d_out, int out_size, void* d_ws, size_t ws_size,
                              hipStream_t stream) {
    const float* h     = (const float*)d_in[0];
    const float* x     = (const float*)d_in[1];
    const int*   ei    = (const int*)d_in[2];     // int32 per harness convention
    const float* mask  = (const float*)d_in[3];
    const float* eattr = (const float*)d_in[4];
    const float* We1   = (const float*)d_in[5];
    const float* be1   = (const float*)d_in[6];
    const float* We2   = (const float*)d_in[7];
    const float* be2   = (const float*)d_in[8];
    const float* Winf  = (const float*)d_in[9];
    const float* binf  = (const float*)d_in[10];
    const float* Wx1   = (const float*)d_in[11];
    const float* bx1   = (const float*)d_in[12];
    const float* Wx2   = (const float*)d_in[13];
    const float* Wn1   = (const float*)d_in[14];
    const float* bn1   = (const float*)d_in[15];
    const float* Wn2   = (const float*)d_in[16];
    const float* bn2   = (const float*)d_in[17];

    // d_out doubles as the accumulator: [NN*H] mi->h_out, [NN*3] dx->x_out.
    float* mi = (float*)d_out;
    float* dx = mi + (size_t)NN * H;

    const int total4 = (NN * H + NN * 3) / 4;   // 6,550,000 / 4
    zero_kernel<<<(total4 + 255) / 256, 256, 0, stream>>>((float4*)d_out, total4);

    edge_kernel<<<NE / EPB, 256, 0, stream>>>(
        h, x, ei, eattr, We1, be1, We2, be2, Winf, binf, Wx1, bx1, Wx2, mi, dx);

    node_kernel<<<(NN + NPB - 1) / NPB, 256, 0, stream>>>(
        h, x, mask, Wn1, bn1, Wn2, bn2, mi, dx);
}

// Round 3
// 609.390 us; speedup vs baseline: 2.7756x; 2.7756x over previous
//
#include <hip/hip_runtime.h>
#include <math.h>

#define NN 50000
#define NE 640000
#define H 128
#define EPB 32        // edges per block
#define NPB 32        // nodes per block
#define ZB 296        // LDS stride (bf16 elems) for z rows; 592 B/row, 16B-aligned, 2-way-max banks
#define BB 136        // LDS stride (bf16 elems) for 128-wide buffers; 272 B/row
#define KP1 288       // padded K for layer 1 (280 -> 288)
#define NZSTR 264     // node kernel fp32 LDS stride
#define BSTR 132      // node kernel fp32 LDS stride

typedef __attribute__((ext_vector_type(8))) unsigned short u16x8;
typedef __attribute__((ext_vector_type(8))) __bf16 bf16x8;
typedef __attribute__((ext_vector_type(4))) float f32x4;

__device__ __forceinline__ float silu_f(float v) {
    return v / (1.0f + __expf(-v));
}

__device__ __forceinline__ unsigned short f2bf(float f) {
    unsigned int u = __builtin_bit_cast(unsigned int, f);
    u += 0x7FFFu + ((u >> 16) & 1u);   // RNE
    return (unsigned short)(u >> 16);
}

__device__ __forceinline__ float bf2f(unsigned short s) {
    unsigned int u = ((unsigned int)s) << 16;
    return __builtin_bit_cast(float, u);
}

__device__ __forceinline__ f32x4 mfma16(u16x8 a, u16x8 b, f32x4 c) {
    return __builtin_amdgcn_mfma_f32_16x16x32_bf16(
        __builtin_bit_cast(bf16x8, a), __builtin_bit_cast(bf16x8, b), c, 0, 0, 0);
}

// ---------------- weight conversion: fp32 [k][n] -> bf16 [n][k] (padded) ----
__global__ __launch_bounds__(256) void convert_weights(
    const float* __restrict__ We1, const float* __restrict__ We2,
    const float* __restrict__ Wx1,
    unsigned short* __restrict__ w1t, unsigned short* __restrict__ w2t,
    unsigned short* __restrict__ wx1t)
{
    int i = blockIdx.x * 256 + threadIdx.x;
    const int S1 = 128 * KP1, S2 = 128 * 128;
    if (i < S1) {
        int n = i / KP1, k = i % KP1;
        w1t[i] = (k < 280) ? f2bf(We1[k * H + n]) : (unsigned short)0;
    } else if (i < S1 + S2) {
        int j = i - S1; int n = j / H, k = j % H;
        w2t[j] = f2bf(We2[k * H + n]);
    } else if (i < S1 + 2 * S2) {
        int j = i - S1 - S2; int n = j / H, k = j % H;
        wx1t[j] = f2bf(Wx1[k * H + n]);
    }
}

__global__ __launch_bounds__(256) void zero_kernel(float4* __restrict__ p, int n4) {
    int i = blockIdx.x * 256 + threadIdx.x;
    if (i < n4) p[i] = make_float4(0.f, 0.f, 0.f, 0.f);
}

// ---------------- edge kernel: MFMA bf16 ------------------------------------
__global__ __launch_bounds__(256, 4) void edge_kernel(
    const float* __restrict__ h, const float* __restrict__ x,
    const int* __restrict__ ei, const float* __restrict__ edge_attr,
    const unsigned short* __restrict__ w1t, const float* __restrict__ be1,
    const unsigned short* __restrict__ w2t, const float* __restrict__ be2,
    const float* __restrict__ Winf, const float* __restrict__ binf,
    const unsigned short* __restrict__ wx1t, const float* __restrict__ bx1,
    const float* __restrict__ Wx2,
    float* __restrict__ mi, float* __restrict__ dx)
{
    __shared__ unsigned short zs[EPB * ZB];   // z input, bf16
    __shared__ unsigned short m1[EPB * BB];   // layer1 out / coord-layer out
    __shared__ unsigned short m2[EPB * BB];   // mij
    __shared__ float relx_s[EPB][3];
    __shared__ float eij_s[EPB];
    __shared__ float xg_s[EPB];
    __shared__ int dst_s[EPB];
    __shared__ int src_s[EPB];

    const int t = threadIdx.x;
    const int e0 = blockIdx.x * EPB;

    if (t < EPB) {
        src_s[t] = ei[e0 + t];
        dst_s[t] = ei[NE + e0 + t];
    }
    __syncthreads();

    // Gather h[dst] -> z[0:128], h[src] -> z[128:256] (bf16); 8 lanes/edge.
    {
        int e = t >> 3, l = t & 7;
        int s = src_s[e], d = dst_s[e];
        const float4* hd = (const float4*)(h + (size_t)d * H);
        const float4* hs = (const float4*)(h + (size_t)s * H);
        unsigned short* zr = zs + e * ZB;
        #pragma unroll
        for (int j = 0; j < 4; j++) {
            float4 v = hd[l * 4 + j];
            ushort4 o = { f2bf(v.x), f2bf(v.y), f2bf(v.z), f2bf(v.w) };
            *(ushort4*)(zr + l * 16 + j * 4) = o;
            float4 w = hs[l * 4 + j];
            ushort4 o2 = { f2bf(w.x), f2bf(w.y), f2bf(w.z), f2bf(w.w) };
            *(ushort4*)(zr + 128 + l * 16 + j * 4) = o2;
        }
    }
    // Geometry + gaussians + edge_attr + zero pad; 1 thread/edge.
    if (t < EPB) {
        int s = src_s[t], d = dst_s[t];
        float rx = x[d * 3 + 0] - x[s * 3 + 0];
        float ry = x[d * 3 + 1] - x[s * 3 + 1];
        float rz = x[d * 3 + 2] - x[s * 3 + 2];
        float d2 = rx * rx + ry * ry + rz * rz;
        float dd = sqrtf(d2 + 1e-8f);
        float inv = 1.0f / (dd + 1.0f);
        relx_s[t][0] = rx * inv;
        relx_s[t][1] = ry * inv;
        relx_s[t][2] = rz * inv;
        const float step = 10.0f / 19.0f;
        const float coeff = -0.5f / (step * step);
        unsigned short* zr = zs + t * ZB;
        #pragma unroll
        for (int g = 0; g < 20; g++) {
            float df = dd - step * (float)g;
            zr[256 + g] = f2bf(__expf(coeff * df * df));
        }
        #pragma unroll
        for (int j = 0; j < 4; j++)
            zr[276 + j] = f2bf(edge_attr[(size_t)(e0 + t) * 4 + j]);
        #pragma unroll
        for (int j = 280; j < ZB; j++) zr[j] = 0;
    }
    __syncthreads();

    const int wv = t >> 6, lane = t & 63;
    const int quad = lane >> 4, r16 = lane & 15;
    const int colg0 = wv * 32 + r16;          // wave's first col-tile column
    const int colg1 = colg0 + 16;

    // ---- Layer 1: z[32][288] @ We1t -> silu -> m1 ----
    {
        f32x4 acc[2][2] = {};
        #pragma unroll
        for (int ks = 0; ks < KP1 / 32; ks++) {
            int ko = ks * 32 + quad * 8;
            u16x8 a0 = *(const u16x8*)(zs + r16 * ZB + ko);
            u16x8 a1 = *(const u16x8*)(zs + (16 + r16) * ZB + ko);
            u16x8 b0 = *(const u16x8*)(w1t + (size_t)colg0 * KP1 + ko);
            u16x8 b1 = *(const u16x8*)(w1t + (size_t)colg1 * KP1 + ko);
            acc[0][0] = mfma16(a0, b0, acc[0][0]);
            acc[0][1] = mfma16(a0, b1, acc[0][1]);
            acc[1][0] = mfma16(a1, b0, acc[1][0]);
            acc[1][1] = mfma16(a1, b1, acc[1][1]);
        }
        #pragma unroll
        for (int ci = 0; ci < 2; ci++) {
            int col = wv * 32 + ci * 16 + r16;
            float bias = be1[col];
            #pragma unroll
            for (int rt = 0; rt < 2; rt++)
                #pragma unroll
                for (int i = 0; i < 4; i++) {
                    int row = rt * 16 + quad * 4 + i;
                    m1[row * BB + col] = f2bf(silu_f(acc[rt][ci][i] + bias));
                }
        }
    }
    __syncthreads();

    // ---- Layer 2: m1 @ We2t -> silu -> m2 (mij) ----
    {
        f32x4 acc[2][2] = {};
        #pragma unroll
        for (int ks = 0; ks < H / 32; ks++) {
            int ko = ks * 32 + quad * 8;
            u16x8 a0 = *(const u16x8*)(m1 + r16 * BB + ko);
            u16x8 a1 = *(const u16x8*)(m1 + (16 + r16) * BB + ko);
            u16x8 b0 = *(const u16x8*)(w2t + (size_t)colg0 * H + ko);
            u16x8 b1 = *(const u16x8*)(w2t + (size_t)colg1 * H + ko);
            acc[0][0] = mfma16(a0, b0, acc[0][0]);
            acc[0][1] = mfma16(a0, b1, acc[0][1]);
            acc[1][0] = mfma16(a1, b0, acc[1][0]);
            acc[1][1] = mfma16(a1, b1, acc[1][1]);
        }
        #pragma unroll
        for (int ci = 0; ci < 2; ci++) {
            int col = wv * 32 + ci * 16 + r16;
            float bias = be2[col];
            #pragma unroll
            for (int rt = 0; rt < 2; rt++)
                #pragma unroll
                for (int i = 0; i < 4; i++) {
                    int row = rt * 16 + quad * 4 + i;
                    m2[row * BB + col] = f2bf(silu_f(acc[rt][ci][i] + bias));
                }
        }
    }
    __syncthreads();

    // ---- eij = sigmoid(mij . Winf + binf); 8 lanes/edge ----
    {
        int e = t >> 3, l = t & 7;
        float s = 0.0f;
        #pragma unroll
        for (int j = 0; j < 16; j++) {
            int k = l + j * 8;
            s += bf2f(m2[e * BB + k]) * Winf[k];
        }
        s += __shfl_down(s, 4, 8);
        s += __shfl_down(s, 2, 8);
        s += __shfl_down(s, 1, 8);
        if (l == 0) eij_s[e] = 1.0f / (1.0f + __expf(-(s + binf[0])));
    }

    // ---- Coord layer: m2 @ Wx1t -> silu -> m1 ----
    {
        f32x4 acc[2][2] = {};
        #pragma unroll
        for (int ks = 0; ks < H / 32; ks++) {
            int ko = ks * 32 + quad * 8;
            u16x8 a0 = *(const u16x8*)(m2 + r16 * BB + ko);
            u16x8 a1 = *(const u16x8*)(m2 + (16 + r16) * BB + ko);
            u16x8 b0 = *(const u16x8*)(wx1t + (size_t)colg0 * H + ko);
            u16x8 b1 = *(const u16x8*)(wx1t + (size_t)colg1 * H + ko);
            acc[0][0] = mfma16(a0, b0, acc[0][0]);
            acc[0][1] = mfma16(a0, b1, acc[0][1]);
            acc[1][0] = mfma16(a1, b0, acc[1][0]);
            acc[1][1] = mfma16(a1, b1, acc[1][1]);
        }
        #pragma unroll
        for (int ci = 0; ci < 2; ci++) {
            int col = wv * 32 + ci * 16 + r16;
            float bias = bx1[col];
            #pragma unroll
            for (int rt = 0; rt < 2; rt++)
                #pragma unroll
                for (int i = 0; i < 4; i++) {
                    int row = rt * 16 + quad * 4 + i;
                    m1[row * BB + col] = f2bf(silu_f(acc[rt][ci][i] + bias));
                }
        }
    }
    __syncthreads();

    // ---- xg = tanh(l3 . Wx2); 8 lanes/edge ----
    {
        int e = t >> 3, l = t & 7;
        float s = 0.0f;
        #pragma unroll
        for (int j = 0; j < 16; j++) {
            int k = l + j * 8;
            s += bf2f(m1[e * BB + k]) * Wx2[k];
        }
        s += __shfl_down(s, 4, 8);
        s += __shfl_down(s, 2, 8);
        s += __shfl_down(s, 1, 8);
        if (l == 0) xg_s[e] = tanhf(s);
    }
    __syncthreads();

    // ---- segment sums via fp32 atomics ----
    {
        int k = t & 127, eh = t >> 7;
        for (int e = eh; e < EPB; e += 2) {
            float mv = bf2f(m2[e * BB + k]) * eij_s[e];
            atomicAdd(&mi[(size_t)dst_s[e] * H + k], mv);
        }
        if (t < EPB * 3) {
            int e = t / 3, dim = t % 3;
            atomicAdd(&dx[(size_t)dst_s[e] * 3 + dim], relx_s[e][dim] * xg_s[e]);
        }
    }
}

// ---------------- node kernel (fp32, unchanged from R2) ---------------------
__device__ __forceinline__ float f4get(const float4& v, int j) {
    return j == 0 ? v.x : (j == 1 ? v.y : (j == 2 ? v.z : v.w));
}

template<int K, int STR>
__device__ __forceinline__ void gemm_tile(const float* __restrict__ in_lds,
                                          const float* __restrict__ W,
                                          int tx, int ty, float acc[4][4]) {
    const float* r0 = in_lds + (ty * 4 + 0) * STR;
    const float* r1 = in_lds + (ty * 4 + 1) * STR;
    const float* r2 = in_lds + (ty * 4 + 2) * STR;
    const float* r3 = in_lds + (ty * 4 + 3) * STR;
    const float* wp = W + tx * 4;
    #pragma unroll 2
    for (int i = 0; i < K; i += 4) {
        float4 z0 = *(const float4*)(r0 + i);
        float4 z1 = *(const float4*)(r1 + i);
        float4 z2 = *(const float4*)(r2 + i);
        float4 z3 = *(const float4*)(r3 + i);
        #pragma unroll
        for (int j = 0; j < 4; j++) {
            float4 w = *(const float4*)(wp + (i + j) * H);
            float a0 = f4get(z0, j), a1 = f4get(z1, j), a2 = f4get(z2, j), a3 = f4get(z3, j);
            acc[0][0] += a0 * w.x; acc[0][1] += a0 * w.y; acc[0][2] += a0 * w.z; acc[0][3] += a0 * w.w;
            acc[1][0] += a1 * w.x; acc[1][1] += a1 * w.y; acc[1][2] += a1 * w.z; acc[1][3] += a1 * w.w;
            acc[2][0] += a2 * w.x; acc[2][1] += a2 * w.y; acc[2][2] += a2 * w.z; acc[2][3] += a2 * w.w;
            acc[3][0] += a3 * w.x; acc[3][1] += a3 * w.y; acc[3][2] += a3 * w.z; acc[3][3] += a3 * w.w;
        }
    }
}

__global__ __launch_bounds__(256) void node_kernel(
    const float* __restrict__ h, const float* __restrict__ x,
    const float* __restrict__ mask,
    const float* __restrict__ Wn1, const float* __restrict__ bn1,
    const float* __restrict__ Wn2, const float* __restrict__ bn2,
    float* __restrict__ mi_hout, float* __restrict__ dx_xout)
{
    __shared__ float nz[NPB * NZSTR];
    __shared__ float buf[NPB * BSTR];

    const int t = threadIdx.x;
    const int n0 = blockIdx.x * NPB;

    {
        int r = t >> 3, l = t & 7;
        int n = n0 + r;
        float4* dst4 = (float4*)(nz + r * NZSTR);
        if (n < NN) {
            const float4* mi4 = (const float4*)(mi_hout + (size_t)n * H);
            const float4* h4  = (const float4*)(h + (size_t)n * H);
            #pragma unroll
            for (int j = 0; j < 4; j++) {
                dst4[l * 4 + j]      = mi4[l * 4 + j];
                dst4[32 + l * 4 + j] = h4[l * 4 + j];
            }
        } else {
            float4 zf = {0.f, 0.f, 0.f, 0.f};
            #pragma unroll
            for (int j = 0; j < 4; j++) {
                dst4[l * 4 + j] = zf;
                dst4[32 + l * 4 + j] = zf;
            }
        }
    }

    float xo = 0.f;
    int xn = -1, xdim = 0;
    if (t < NPB * 3) {
        int r = t / 3; xdim = t % 3;
        int n = n0 + r;
        if (n < NN) {
            xn = n;
            xo = x[(size_t)n * 3 + xdim] + dx_xout[(size_t)n * 3 + xdim] * mask[n];
        }
    }
    __syncthreads();

    if (xn >= 0) dx_xout[(size_t)xn * 3 + xdim] = xo;

    const int tx = t & 31, ty = t >> 5;

    {
        float acc[4][4] = {{0}};
        gemm_tile<2 * H, NZSTR>(nz, Wn1, tx, ty, acc);
        float4 b = *(const float4*)(bn1 + tx * 4);
        #pragma unroll
        for (int e = 0; e < 4; e++) {
            float4 o;
            o.x = silu_f(acc[e][0] + b.x);
            o.y = silu_f(acc[e][1] + b.y);
            o.z = silu_f(acc[e][2] + b.z);
            o.w = silu_f(acc[e][3] + b.w);
            *(float4*)(buf + (ty * 4 + e) * BSTR + tx * 4) = o;
        }
    }
    __syncthreads();

    {
        float acc[4][4] = {{0}};
        gemm_tile<H, BSTR>(buf, Wn2, tx, ty, acc);
        float4 b = *(const float4*)(bn2 + tx * 4);
        #pragma unroll
        for (int e = 0; e < 4; e++) {
            int n = n0 + ty * 4 + e;
            if (n < NN) {
                const float4 hv = *(const float4*)(h + (size_t)n * H + tx * 4);
                float4 o;
                o.x = hv.x + acc[e][0] + b.x;
                o.y = hv.y + acc[e][1] + b.y;
                o.z = hv.z + acc[e][2] + b.z;
                o.w = hv.w + acc[e][3] + b.w;
                *(float4*)(mi_hout + (size_t)n * H + tx * 4) = o;
            }
        }
    }
}

extern "C" void kernel_launch(void* const* d_in, const int* in_sizes, int n_in,
                              void* d_out, int out_size, void* d_ws, size_t ws_size,
                              hipStream_t stream) {
    const float* h     = (const float*)d_in[0];
    const float* x     = (const float*)d_in[1];
    const int*   ei    = (const int*)d_in[2];
    const float* mask  = (const float*)d_in[3];
    const float* eattr = (const float*)d_in[4];
    const float* We1   = (const float*)d_in[5];
    const float* be1   = (const float*)d_in[6];
    const float* We2   = (const float*)d_in[7];
    const float* be2   = (const float*)d_in[8];
    const float* Winf  = (const float*)d_in[9];
    const float* binf  = (const float*)d_in[10];
    const float* Wx1   = (const float*)d_in[11];
    const float* bx1   = (const float*)d_in[12];
    const float* Wx2   = (const float*)d_in[13];
    const float* Wn1   = (const float*)d_in[14];
    const float* bn1   = (const float*)d_in[15];
    const float* Wn2   = (const float*)d_in[16];
    const float* bn2   = (const float*)d_in[17];

    // d_out doubles as accumulator: [NN*H] mi->h_out, [NN*3] dx->x_out.
    float* mi = (float*)d_out;
    float* dx = mi + (size_t)NN * H;

    // bf16 transposed weights in workspace.
    unsigned short* w1t  = (unsigned short*)d_ws;              // 128*288
    unsigned short* w2t  = w1t + 128 * KP1;                    // 128*128
    unsigned short* wx1t = w2t + 128 * H;                      // 128*128

    const int wconv_total = 128 * KP1 + 2 * 128 * H;
    convert_weights<<<(wconv_total + 255) / 256, 256, 0, stream>>>(
        We1, We2, Wx1, w1t, w2t, wx1t);

    const int total4 = (NN * H + NN * 3) / 4;
    zero_kernel<<<(total4 + 255) / 256, 256, 0, stream>>>((float4*)d_out, total4);

    edge_kernel<<<NE / EPB, 256, 0, stream>>>(
        h, x, ei, eattr, w1t, be1, w2t, be2, Winf, binf, wx1t, bx1, Wx2, mi, dx);

    node_kernel<<<(NN + NPB - 1) / NPB, 256, 0, stream>>>(
        h, x, mask, Wn1, bn1, Wn2, bn2, mi, dx);
}

// Round 4
// 525.014 us; speedup vs baseline: 3.2216x; 1.1607x over previous
//
#include <hip/hip_runtime.h>
#include <math.h>

#define NN 50000
#define NE 640000
#define H 128
#define EPB 32        // edges per block
#define NPB 32        // nodes per block
#define ZB 296        // LDS stride (bf16) for z rows (592 B, 16B-aligned, conflict-benign)
#define BB 136        // LDS stride (bf16) for 128-wide buffers (272 B)
#define KP1 288       // padded K for layer 1 (280 -> 288)
#define NZB 264       // LDS stride (bf16) for node 256-wide input (528 B)

typedef __attribute__((ext_vector_type(8))) unsigned short u16x8;
typedef __attribute__((ext_vector_type(8))) __bf16 bf16x8;
typedef __attribute__((ext_vector_type(2))) __bf16 bf16x2;
typedef __attribute__((ext_vector_type(4))) float f32x4;

__device__ __forceinline__ float silu_f(float v) {
    return v / (1.0f + __expf(-v));
}

__device__ __forceinline__ unsigned short f2bf(float f) {
    unsigned int u = __builtin_bit_cast(unsigned int, f);
    u += 0x7FFFu + ((u >> 16) & 1u);   // RNE
    return (unsigned short)(u >> 16);
}

__device__ __forceinline__ float bf2f(unsigned short s) {
    unsigned int u = ((unsigned int)s) << 16;
    return __builtin_bit_cast(float, u);
}

// Packed f32x2 -> bf16x2 (low = first arg). HW v_cvt_pk_bf16_f32 on gfx950.
__device__ __forceinline__ unsigned int pkbf(float lo, float hi) {
#if __has_builtin(__builtin_amdgcn_cvt_pk_bf16_f32)
    bf16x2 v = __builtin_amdgcn_cvt_pk_bf16_f32(lo, hi);
    unsigned int r; __builtin_memcpy(&r, &v, 4); return r;
#else
    return (unsigned int)f2bf(lo) | ((unsigned int)f2bf(hi) << 16);
#endif
}

__device__ __forceinline__ f32x4 mfma16(u16x8 a, u16x8 b, f32x4 c) {
    return __builtin_amdgcn_mfma_f32_16x16x32_bf16(
        __builtin_bit_cast(bf16x8, a), __builtin_bit_cast(bf16x8, b), c, 0, 0, 0);
}

// GEMM tile with transposed roles: D = W^T (A) x in^T (B) -> D[feature][edge].
// Lane (quad,r16) of wave wv holds, per (rt,ci): features wv*32+rt*16+quad*4..+3
// for edge ci*16+r16. Epilogue: silu+bias -> packed 8B LDS write (outbuf stride BB).
template<int KT, int INSTR, bool SYNC_BEFORE_EPI>
__device__ __forceinline__ void layer_mfma(
    const unsigned short* __restrict__ inbuf,   // [32][INSTR] bf16 (rows = edges)
    const unsigned short* __restrict__ wt,      // [128][KT] bf16 (W^T)
    const float* __restrict__ bias,             // [128]
    unsigned short* __restrict__ outbuf,        // [32][BB] bf16
    int wv, int quad, int r16)
{
    f32x4 acc[2][2] = {};
    const int F = wv * 32;
    #pragma unroll
    for (int ks = 0; ks < KT / 32; ks++) {
        int ko = ks * 32 + quad * 8;
        u16x8 b0 = *(const u16x8*)(inbuf + r16 * INSTR + ko);
        u16x8 b1 = *(const u16x8*)(inbuf + (16 + r16) * INSTR + ko);
        u16x8 a0 = *(const u16x8*)(wt + (size_t)(F + r16) * KT + ko);
        u16x8 a1 = *(const u16x8*)(wt + (size_t)(F + 16 + r16) * KT + ko);
        acc[0][0] = mfma16(a0, b0, acc[0][0]);
        acc[0][1] = mfma16(a0, b1, acc[0][1]);
        acc[1][0] = mfma16(a1, b0, acc[1][0]);
        acc[1][1] = mfma16(a1, b1, acc[1][1]);
    }
    if (SYNC_BEFORE_EPI) __syncthreads();
    #pragma unroll
    for (int rt = 0; rt < 2; rt++) {
        int f0 = F + rt * 16 + quad * 4;
        float4 bv = *(const float4*)(bias + f0);
        #pragma unroll
        for (int ci = 0; ci < 2; ci++) {
            int e = ci * 16 + r16;
            float s0 = silu_f(acc[rt][ci][0] + bv.x);
            float s1 = silu_f(acc[rt][ci][1] + bv.y);
            float s2 = silu_f(acc[rt][ci][2] + bv.z);
            float s3 = silu_f(acc[rt][ci][3] + bv.w);
            uint2 p = { pkbf(s0, s1), pkbf(s2, s3) };
            *(uint2*)(outbuf + e * BB + f0) = p;
        }
    }
}

// ---------------- weight conversion: fp32 [k][n] -> bf16 [n][k] -------------
__global__ __launch_bounds__(256) void convert_weights(
    const float* __restrict__ We1, const float* __restrict__ We2,
    const float* __restrict__ Wx1, const float* __restrict__ Wn1,
    const float* __restrict__ Wn2,
    unsigned short* __restrict__ w1t, unsigned short* __restrict__ w2t,
    unsigned short* __restrict__ wx1t, unsigned short* __restrict__ wn1t,
    unsigned short* __restrict__ wn2t)
{
    int i = blockIdx.x * 256 + threadIdx.x;
    const int S1 = 128 * KP1;          // 36864
    const int S2 = 128 * 128;          // 16384
    const int S3 = 128 * 256;          // 32768
    if (i < S1) {
        int n = i / KP1, k = i % KP1;
        w1t[i] = (k < 280) ? f2bf(We1[k * H + n]) : (unsigned short)0;
    } else if (i < S1 + S2) {
        int j = i - S1; int n = j / H, k = j % H;
        w2t[j] = f2bf(We2[k * H + n]);
    } else if (i < S1 + 2 * S2) {
        int j = i - S1 - S2; int n = j / H, k = j % H;
        wx1t[j] = f2bf(Wx1[k * H + n]);
    } else if (i < S1 + 2 * S2 + S3) {
        int j = i - S1 - 2 * S2; int n = j / 256, k = j % 256;
        wn1t[j] = f2bf(Wn1[k * H + n]);
    } else if (i < S1 + 3 * S2 + S3) {
        int j = i - S1 - 2 * S2 - S3; int n = j / H, k = j % H;
        wn2t[j] = f2bf(Wn2[k * H + n]);
    }
}

__global__ __launch_bounds__(256) void zero_kernel(float4* __restrict__ p, int n4) {
    int i = blockIdx.x * 256 + threadIdx.x;
    if (i < n4) p[i] = make_float4(0.f, 0.f, 0.f, 0.f);
}

// ---------------- edge kernel -----------------------------------------------
__global__ __launch_bounds__(256, 5) void edge_kernel(
    const float* __restrict__ h, const float* __restrict__ x,
    const int* __restrict__ ei, const float* __restrict__ edge_attr,
    const unsigned short* __restrict__ w1t, const float* __restrict__ be1,
    const unsigned short* __restrict__ w2t, const float* __restrict__ be2,
    const float* __restrict__ Winf, const float* __restrict__ binf,
    const unsigned short* __restrict__ wx1t, const float* __restrict__ bx1,
    const float* __restrict__ Wx2,
    float* __restrict__ mi, float* __restrict__ dx)
{
    __shared__ unsigned short zs[EPB * ZB];   // z input; first 32*BB aliased as m1
    __shared__ unsigned short m2[EPB * BB];   // mij
    __shared__ float relx_s[EPB][3];
    __shared__ float eij_s[EPB];
    __shared__ float xg_s[EPB];
    __shared__ int dst_s[EPB];
    __shared__ int src_s[EPB];
    __shared__ float winf_s[H];
    __shared__ float wx2_s[H];

    unsigned short* m1 = zs;   // alias: zs dead after layer-1 K-loop (+barrier)

    const int t = threadIdx.x;
    const int e0 = blockIdx.x * EPB;

    if (t < EPB) {
        src_s[t] = ei[e0 + t];
        dst_s[t] = ei[NE + e0 + t];
    }
    if (t >= 128 && t < 256) {
        winf_s[t - 128] = Winf[t - 128];
        wx2_s[t - 128] = Wx2[t - 128];
    }
    __syncthreads();                                               // A

    // Gather h[dst] -> z[0:128], h[src] -> z[128:256]; 8 lanes/edge.
    {
        int e = t >> 3, l = t & 7;
        int s = src_s[e], d = dst_s[e];
        const float4* hd = (const float4*)(h + (size_t)d * H);
        const float4* hs = (const float4*)(h + (size_t)s * H);
        unsigned short* zr = zs + e * ZB;
        float4 v0 = hd[l * 4 + 0], v1 = hd[l * 4 + 1];
        float4 v2 = hd[l * 4 + 2], v3 = hd[l * 4 + 3];
        uint4 p0 = { pkbf(v0.x, v0.y), pkbf(v0.z, v0.w), pkbf(v1.x, v1.y), pkbf(v1.z, v1.w) };
        uint4 p1 = { pkbf(v2.x, v2.y), pkbf(v2.z, v2.w), pkbf(v3.x, v3.y), pkbf(v3.z, v3.w) };
        *(uint4*)(zr + l * 16) = p0;
        *(uint4*)(zr + l * 16 + 8) = p1;
        float4 w0 = hs[l * 4 + 0], w1 = hs[l * 4 + 1];
        float4 w2 = hs[l * 4 + 2], w3 = hs[l * 4 + 3];
        uint4 q0 = { pkbf(w0.x, w0.y), pkbf(w0.z, w0.w), pkbf(w1.x, w1.y), pkbf(w1.z, w1.w) };
        uint4 q1 = { pkbf(w2.x, w2.y), pkbf(w2.z, w2.w), pkbf(w3.x, w3.y), pkbf(w3.z, w3.w) };
        *(uint4*)(zr + 128 + l * 16) = q0;
        *(uint4*)(zr + 128 + l * 16 + 8) = q1;
    }
    // Geometry + gaussians + edge_attr + pad; 1 thread/edge.
    if (t < EPB) {
        int s = src_s[t], d = dst_s[t];
        float rx = x[d * 3 + 0] - x[s * 3 + 0];
        float ry = x[d * 3 + 1] - x[s * 3 + 1];
        float rz = x[d * 3 + 2] - x[s * 3 + 2];
        float d2 = rx * rx + ry * ry + rz * rz;
        float dd = sqrtf(d2 + 1e-8f);
        float inv = 1.0f / (dd + 1.0f);
        relx_s[t][0] = rx * inv;
        relx_s[t][1] = ry * inv;
        relx_s[t][2] = rz * inv;
        const float step = 10.0f / 19.0f;
        const float coeff = -0.5f / (step * step);
        unsigned short* zr = zs + t * ZB;
        #pragma unroll
        for (int g = 0; g < 20; g++) {
            float df = dd - step * (float)g;
            zr[256 + g] = f2bf(__expf(coeff * df * df));
        }
        #pragma unroll
        for (int j = 0; j < 4; j++)
            zr[276 + j] = f2bf(edge_attr[(size_t)(e0 + t) * 4 + j]);
        #pragma unroll
        for (int j = 280; j < ZB; j++) zr[j] = 0;
    }
    __syncthreads();                                               // B

    const int wv = t >> 6, lane = t & 63;
    const int quad = lane >> 4, r16 = lane & 15;

    // Layer 1: (z @ We1)^T, sync before epilogue (m1 aliases zs)
    layer_mfma<KP1, ZB, true>(zs, w1t, be1, m1, wv, quad, r16);    // C inside
    __syncthreads();                                               // D

    // Layer 2: mij
    layer_mfma<H, BB, false>(m1, w2t, be2, m2, wv, quad, r16);
    __syncthreads();                                               // E

    // eij = sigmoid(mij . Winf + binf); 8 lanes/edge, vector LDS reads.
    {
        int e = t >> 3, l = t & 7;
        const unsigned short* row = m2 + e * BB + l * 16;
        u16x8 v0 = *(const u16x8*)(row);
        u16x8 v1 = *(const u16x8*)(row + 8);
        float s = 0.0f;
        #pragma unroll
        for (int j = 0; j < 8; j++) {
            s += bf2f(v0[j]) * winf_s[l * 16 + j];
            s += bf2f(v1[j]) * winf_s[l * 16 + 8 + j];
        }
        s += __shfl_down(s, 4, 8);
        s += __shfl_down(s, 2, 8);
        s += __shfl_down(s, 1, 8);
        if (l == 0) eij_s[e] = 1.0f / (1.0f + __expf(-(s + binf[0])));
    }

    // Coord layer: silu(mij @ Wx1) -> m1 (reads m2, writes m1: no alias hazard)
    layer_mfma<H, BB, false>(m2, wx1t, bx1, m1, wv, quad, r16);
    __syncthreads();                                               // F

    // xg = tanh(l3 . Wx2); 8 lanes/edge.
    {
        int e = t >> 3, l = t & 7;
        const unsigned short* row = m1 + e * BB + l * 16;
        u16x8 v0 = *(const u16x8*)(row);
        u16x8 v1 = *(const u16x8*)(row + 8);
        float s = 0.0f;
        #pragma unroll
        for (int j = 0; j < 8; j++) {
            s += bf2f(v0[j]) * wx2_s[l * 16 + j];
            s += bf2f(v1[j]) * wx2_s[l * 16 + 8 + j];
        }
        s += __shfl_down(s, 4, 8);
        s += __shfl_down(s, 2, 8);
        s += __shfl_down(s, 1, 8);
        if (l == 0) xg_s[e] = tanhf(s);
    }
    __syncthreads();                                               // G

    // Segment sums via fp32 atomics.
    {
        int k = t & 127, eh = t >> 7;
        for (int e = eh; e < EPB; e += 2) {
            float mv = bf2f(m2[e * BB + k]) * eij_s[e];
            atomicAdd(&mi[(size_t)dst_s[e] * H + k], mv);
        }
        if (t < EPB * 3) {
            int e = t / 3, dim = t % 3;
            atomicAdd(&dx[(size_t)dst_s[e] * 3 + dim], relx_s[e][dim] * xg_s[e]);
        }
    }
}

// ---------------- node kernel (bf16 MFMA) -----------------------------------
__global__ __launch_bounds__(256, 6) void node_kernel(
    const float* __restrict__ h, const float* __restrict__ x,
    const float* __restrict__ mask,
    const unsigned short* __restrict__ wn1t, const float* __restrict__ bn1,
    const unsigned short* __restrict__ wn2t, const float* __restrict__ bn2,
    float* __restrict__ mi_hout, float* __restrict__ dx_xout)
{
    __shared__ unsigned short nzs[NPB * NZB];   // [mi, h] bf16
    __shared__ unsigned short nbuf[NPB * BB];

    const int t = threadIdx.x;
    const int n0 = blockIdx.x * NPB;

    // Load nz = [mi, h] -> bf16; 8 lanes/node.
    {
        int r = t >> 3, l = t & 7;
        int n = n0 + r;
        unsigned short* zr = nzs + r * NZB;
        if (n < NN) {
            const float4* mi4 = (const float4*)(mi_hout + (size_t)n * H);
            const float4* h4  = (const float4*)(h + (size_t)n * H);
            float4 v0 = mi4[l * 4 + 0], v1 = mi4[l * 4 + 1];
            float4 v2 = mi4[l * 4 + 2], v3 = mi4[l * 4 + 3];
            uint4 p0 = { pkbf(v0.x, v0.y), pkbf(v0.z, v0.w), pkbf(v1.x, v1.y), pkbf(v1.z, v1.w) };
            uint4 p1 = { pkbf(v2.x, v2.y), pkbf(v2.z, v2.w), pkbf(v3.x, v3.y), pkbf(v3.z, v3.w) };
            *(uint4*)(zr + l * 16) = p0;
            *(uint4*)(zr + l * 16 + 8) = p1;
            float4 w0 = h4[l * 4 + 0], w1 = h4[l * 4 + 1];
            float4 w2 = h4[l * 4 + 2], w3 = h4[l * 4 + 3];
            uint4 q0 = { pkbf(w0.x, w0.y), pkbf(w0.z, w0.w), pkbf(w1.x, w1.y), pkbf(w1.z, w1.w) };
            uint4 q1 = { pkbf(w2.x, w2.y), pkbf(w2.z, w2.w), pkbf(w3.x, w3.y), pkbf(w3.z, w3.w) };
            *(uint4*)(zr + 128 + l * 16) = q0;
            *(uint4*)(zr + 128 + l * 16 + 8) = q1;
        } else {
            uint4 zf = {0u, 0u, 0u, 0u};
            *(uint4*)(zr + l * 16) = zf;
            *(uint4*)(zr + l * 16 + 8) = zf;
            *(uint4*)(zr + 128 + l * 16) = zf;
            *(uint4*)(zr + 128 + l * 16 + 8) = zf;
        }
    }

    // x_out = x + dx * mask : read dx before barrier, write after.
    float xo = 0.f;
    int xn = -1, xdim = 0;
    if (t < NPB * 3) {
        int r = t / 3; xdim = t % 3;
        int n = n0 + r;
        if (n < NN) {
            xn = n;
            xo = x[(size_t)n * 3 + xdim] + dx_xout[(size_t)n * 3 + xdim] * mask[n];
        }
    }
    __syncthreads();

    if (xn >= 0) dx_xout[(size_t)xn * 3 + xdim] = xo;

    const int wv = t >> 6, lane = t & 63;
    const int quad = lane >> 4, r16 = lane & 15;

    // Layer n1: silu(nz @ Wn1) -> nbuf
    layer_mfma<2 * H, NZB, false>(nzs, wn1t, bn1, nbuf, wv, quad, r16);
    __syncthreads();

    // Layer n2 + residual: h_out = h + nbuf @ Wn2 + bn2 (in place over mi)
    {
        f32x4 acc[2][2] = {};
        const int F = wv * 32;
        #pragma unroll
        for (int ks = 0; ks < H / 32; ks++) {
            int ko = ks * 32 + quad * 8;
            u16x8 b0 = *(const u16x8*)(nbuf + r16 * BB + ko);
            u16x8 b1 = *(const u16x8*)(nbuf + (16 + r16) * BB + ko);
            u16x8 a0 = *(const u16x8*)(wn2t + (size_t)(F + r16) * H + ko);
            u16x8 a1 = *(const u16x8*)(wn2t + (size_t)(F + 16 + r16) * H + ko);
            acc[0][0] = mfma16(a0, b0, acc[0][0]);
            acc[0][1] = mfma16(a0, b1, acc[0][1]);
            acc[1][0] = mfma16(a1, b0, acc[1][0]);
            acc[1][1] = mfma16(a1, b1, acc[1][1]);
        }
        #pragma unroll
        for (int rt = 0; rt < 2; rt++) {
            int f0 = F + rt * 16 + quad * 4;
            float4 bv = *(const float4*)(bn2 + f0);
            #pragma unroll
            for (int ci = 0; ci < 2; ci++) {
                int n = n0 + ci * 16 + r16;
                if (n < NN) {
                    float4 hv = *(const float4*)(h + (size_t)n * H + f0);
                    float4 o;
                    o.x = hv.x + acc[rt][ci][0] + bv.x;
                    o.y = hv.y + acc[rt][ci][1] + bv.y;
                    o.z = hv.z + acc[rt][ci][2] + bv.z;
                    o.w = hv.w + acc[rt][ci][3] + bv.w;
                    *(float4*)(mi_hout + (size_t)n * H + f0) = o;
                }
            }
        }
    }
}

extern "C" void kernel_launch(void* const* d_in, const int* in_sizes, int n_in,
                              void* d_out, int out_size, void* d_ws, size_t ws_size,
                              hipStream_t stream) {
    const float* h     = (const float*)d_in[0];
    const float* x     = (const float*)d_in[1];
    const int*   ei    = (const int*)d_in[2];
    const float* mask  = (const float*)d_in[3];
    const float* eattr = (const float*)d_in[4];
    const float* We1   = (const float*)d_in[5];
    const float* be1   = (const float*)d_in[6];
    const float* We2   = (const float*)d_in[7];
    const float* be2   = (const float*)d_in[8];
    const float* Winf  = (const float*)d_in[9];
    const float* binf  = (const float*)d_in[10];
    const float* Wx1   = (const float*)d_in[11];
    const float* bx1   = (const float*)d_in[12];
    const float* Wx2   = (const float*)d_in[13];
    const float* Wn1   = (const float*)d_in[14];
    const float* bn1   = (const float*)d_in[15];
    const float* Wn2   = (const float*)d_in[16];
    const float* bn2   = (const float*)d_in[17];

    // d_out doubles as accumulator: [NN*H] mi->h_out, [NN*3] dx->x_out.
    float* mi = (float*)d_out;
    float* dx = mi + (size_t)NN * H;

    // bf16 transposed weights in workspace.
    unsigned short* w1t  = (unsigned short*)d_ws;        // 128*288
    unsigned short* w2t  = w1t + 128 * KP1;              // 128*128
    unsigned short* wx1t = w2t + 128 * H;                // 128*128
    unsigned short* wn1t = wx1t + 128 * H;               // 128*256
    unsigned short* wn2t = wn1t + 128 * 256;             // 128*128

    const int wconv_total = 128 * KP1 + 3 * 128 * H + 128 * 256;
    convert_weights<<<(wconv_total + 255) / 256, 256, 0, stream>>>(
        We1, We2, Wx1, Wn1, Wn2, w1t, w2t, wx1t, wn1t, wn2t);

    const int total4 = (NN * H + NN * 3) / 4;
    zero_kernel<<<(total4 + 255) / 256, 256, 0, stream>>>((float4*)d_out, total4);

    edge_kernel<<<NE / EPB, 256, 0, stream>>>(
        h, x, ei, eattr, w1t, be1, w2t, be2, Winf, binf, wx1t, bx1, Wx2, mi, dx);

    node_kernel<<<(NN + NPB - 1) / NPB, 256, 0, stream>>>(
        h, x, mask, wn1t, bn1, wn2t, bn2, mi, dx);
}